// Round 1
// baseline (858.922 us; speedup 1.0000x reference)
//
#include <hip/hip_runtime.h>
#include <hip/hip_bf16.h>

typedef __attribute__((ext_vector_type(8))) short bf16x8;
typedef __attribute__((ext_vector_type(4))) float f32x4;

#define NWIN   4096
#define NTOK   49
#define DMODEL 256
#define NHEAD  8
#define DHEAD  32
#define NKEY   53          // 4 mem + 49 tokens
#define LDX    264         // xn / At row stride in shorts (pad +8: bank step 4 -> 2-way free)
#define LDQK   40          // q/k row stride (pad +8: 80B rows, bank step 20 -> 2-way free)
#define LDP    72          // P row stride
#define LDVT   72          // v^T row stride
#define QK_SHORTS 2560     // 64*40
#define VT_SHORTS 2304     // 32*72
#define PERHEAD   7424     // q + k + vT (shorts); P (64*72=4608) overlays q+k (5120)
#define LDS_SHORTS (PERHEAD * 8)
#define LDS_BYTES  (LDS_SHORTS * 2)   // 118784 B; xn (64*264=16896 sh) overlays heads 0-2

__device__ __forceinline__ short f2bf(float f) {  // RNE float->bf16
  unsigned u = __float_as_uint(f);
  unsigned r = (u + 0x7fffu + ((u >> 16) & 1u)) >> 16;
  return (short)r;
}

__device__ __forceinline__ f32x4 mfma16(bf16x8 a, bf16x8 b, f32x4 c) {
  return __builtin_amdgcn_mfma_f32_16x16x32_bf16(a, b, c, 0, 0, 0);
}

// ---- weight transpose + bf16 cast: wqT[n][k] = wqkv[k][n]; woT[n][k] = wout[k][n]
__global__ void k_convert(const float* __restrict__ wqkv, const float* __restrict__ wout,
                          short* __restrict__ wqT, short* __restrict__ woT) {
  int idx = blockIdx.x * 256 + threadIdx.x;
  if (idx < 768 * 256) {
    int n = idx >> 8, k = idx & 255;
    wqT[idx] = f2bf(wqkv[k * 768 + n]);
  }
  if (idx < 256 * 256) {
    int n = idx >> 8, k = idx & 255;
    woT[idx] = f2bf(wout[k * 256 + n]);
  }
}

// ---- fused LN + QKV GEMM + window attention. 1 block/window, wave w = head w.
__global__ __launch_bounds__(512, 2) void k_attn(
    const float* __restrict__ x, const float* __restrict__ gamma,
    const short* __restrict__ wqT, const float* __restrict__ memkv,
    const float* __restrict__ btab, short* __restrict__ aout) {
  extern __shared__ short lds[];
  const int tid = threadIdx.x;
  const int wv = tid >> 6;        // head
  const int lane = tid & 63;
  const int lhi = lane >> 4, llo = lane & 15;
  const int win = blockIdx.x;

  // zero xn region (incl. pad rows 49..63 -> zero q/k/v for pad tokens)
  {
    int* w = (int*)lds;
    for (int j = tid; j < 64 * LDX / 2; j += 512) w[j] = 0;
  }
  __syncthreads();

  // LayerNorm -> xn bf16 [64][LDX]
  const float* xwin = x + (size_t)win * (NTOK * DMODEL);
  const float4 g4 = ((const float4*)gamma)[lane];
  for (int row = wv; row < NTOK; row += 8) {
    float4 v = ((const float4*)(xwin + row * DMODEL))[lane];
    float s = v.x + v.y + v.z + v.w;
#pragma unroll
    for (int m = 1; m < 64; m <<= 1) s += __shfl_xor(s, m);
    float mu = s * (1.0f / 256.0f);
    float dx = v.x - mu, dy = v.y - mu, dz = v.z - mu, dw = v.w - mu;
    float s2 = dx * dx + dy * dy + dz * dz + dw * dw;
#pragma unroll
    for (int m = 1; m < 64; m <<= 1) s2 += __shfl_xor(s2, m);
    float rs = rsqrtf(s2 * (1.0f / 256.0f) + 1e-5f);
    short4 o;
    o.x = f2bf(dx * rs * g4.x); o.y = f2bf(dy * rs * g4.y);
    o.z = f2bf(dz * rs * g4.z); o.w = f2bf(dw * rs * g4.w);
    *(short4*)&lds[row * LDX + lane * 4] = o;
  }
  __syncthreads();

  // QKV GEMM: this wave's head cols {q,k,v} = 6 N-tiles, M=64, K=256
  const int h = wv;
  f32x4 acc[4][6] = {};
  {
    const int nr = h * 32 + llo;
    const int nrow[6] = {nr, nr + 16, nr + 256, nr + 272, nr + 512, nr + 528};
    for (int ks = 0; ks < 8; ++ks) {
      bf16x8 a[4];
#pragma unroll
      for (int mt = 0; mt < 4; ++mt)
        a[mt] = *(const bf16x8*)&lds[(mt * 16 + llo) * LDX + ks * 32 + lhi * 8];
#pragma unroll
      for (int nt = 0; nt < 6; ++nt) {
        bf16x8 b = *(const bf16x8*)&wqT[nrow[nt] * 256 + ks * 32 + lhi * 8];
#pragma unroll
        for (int mt = 0; mt < 4; ++mt) acc[mt][nt] = mfma16(a[mt], b, acc[mt][nt]);
      }
    }
  }
  __syncthreads();  // all waves done with xn; per-head regions may overlay it

  short* qh = lds + wv * PERHEAD;       // [64][40]  queries (scaled)
  short* kh = qh + QK_SHORTS;           // [64][40]  keys: 0..3 mem, 4..52 tokens
  short* vth = kh + QK_SHORTS;          // [32][72]  v transposed [d][key]
  short* Ph = qh;                       // [64][72]  P overlays q+k after QK^T

  {  // zero per-head region (pad rows/cols must be finite/zero)
    int* w = (int*)qh;
    for (int i = lane; i < PERHEAD / 2; i += 64) w[i] = 0;
  }

  // scatter q,k,v from D-layout accs (row = mt*16 + lhi*4 + r, col = nt*16 + llo)
  const float qscale = 0.17677669529663687f;  // 32^-0.5
#pragma unroll
  for (int mt = 0; mt < 4; ++mt)
#pragma unroll
    for (int r = 0; r < 4; ++r) {
      int row = mt * 16 + lhi * 4 + r;
      if (row < NTOK) {
        qh[row * LDQK + llo]            = f2bf(acc[mt][0][r] * qscale);
        qh[row * LDQK + 16 + llo]       = f2bf(acc[mt][1][r] * qscale);
        kh[(row + 4) * LDQK + llo]      = f2bf(acc[mt][2][r]);
        kh[(row + 4) * LDQK + 16 + llo] = f2bf(acc[mt][3][r]);
        vth[llo * LDVT + row + 4]        = f2bf(acc[mt][4][r]);
        vth[(llo + 16) * LDVT + row + 4] = f2bf(acc[mt][5][r]);
      }
    }
  // memory kv rows
#pragma unroll
  for (int i = 0; i < 2; ++i) {
    int e = lane + i * 64;  // 0..127
    int m = e >> 5, d = e & 31;
    kh[m * LDQK + d]  = f2bf(memkv[(h * 4 + m) * 32 + d]);
    vth[d * LDVT + m] = f2bf(memkv[1024 + (h * 4 + m) * 32 + d]);
  }

  // QK^T: M=64 queries, N=64 keys (53 valid), K=32 (single step)
  f32x4 sim[4][4] = {};
  {
    bf16x8 qa[4], kb[4];
#pragma unroll
    for (int mt = 0; mt < 4; ++mt)
      qa[mt] = *(const bf16x8*)&qh[(mt * 16 + llo) * LDQK + lhi * 8];
#pragma unroll
    for (int nt = 0; nt < 4; ++nt)
      kb[nt] = *(const bf16x8*)&kh[(nt * 16 + llo) * LDQK + lhi * 8];
#pragma unroll
    for (int nt = 0; nt < 4; ++nt)
#pragma unroll
      for (int mt = 0; mt < 4; ++mt) sim[mt][nt] = mfma16(qa[mt], kb[nt], sim[mt][nt]);
  }

  // bias + mask + softmax -> normalized P bf16 (row owned by 16 lanes sharing lhi)
#pragma unroll
  for (int mt = 0; mt < 4; ++mt)
#pragma unroll
    for (int r = 0; r < 4; ++r) {
      const int qt = mt * 16 + lhi * 4 + r;
      const bool qv = qt < NTOK;
      const int qa_ = qt / 7, qb_ = qt % 7;
      float vals[4];
#pragma unroll
      for (int nt = 0; nt < 4; ++nt) {
        int col = nt * 16 + llo;
        float sv = sim[mt][nt][r];
        if (col >= NKEY) sv = -1e30f;                 // pad keys
        else if (qv && col >= 4) {                    // rel-pos bias (mem keys: 0)
          int t = col - 4;
          int r0 = qa_ - t / 7 + 6, r1 = qb_ - t % 7 + 6;
          sv += btab[(r0 * 13 + r1) * NHEAD + h];
        }
        vals[nt] = sv;
      }
      float mx = fmaxf(fmaxf(vals[0], vals[1]), fmaxf(vals[2], vals[3]));
#pragma unroll
      for (int m = 1; m < 16; m <<= 1) mx = fmaxf(mx, __shfl_xor(mx, m));
      float p[4], sum = 0.f;
#pragma unroll
      for (int nt = 0; nt < 4; ++nt) { p[nt] = __expf(vals[nt] - mx); sum += p[nt]; }
#pragma unroll
      for (int m = 1; m < 16; m <<= 1) sum += __shfl_xor(sum, m);
      float inv = 1.0f / sum;
#pragma unroll
      for (int nt = 0; nt < 4; ++nt)
        Ph[qt * LDP + nt * 16 + llo] = f2bf(p[nt] * inv);
    }

  // PV: M=64 queries, N=32 dims, K=64 keys (2 steps)
  f32x4 oacc[4][2] = {};
#pragma unroll
  for (int ks = 0; ks < 2; ++ks) {
    bf16x8 pa[4];
#pragma unroll
    for (int mt = 0; mt < 4; ++mt)
      pa[mt] = *(const bf16x8*)&Ph[(mt * 16 + llo) * LDP + ks * 32 + lhi * 8];
#pragma unroll
    for (int nt = 0; nt < 2; ++nt) {
      bf16x8 vb = *(const bf16x8*)&vth[(nt * 16 + llo) * LDVT + ks * 32 + lhi * 8];
#pragma unroll
      for (int mt = 0; mt < 4; ++mt) oacc[mt][nt] = mfma16(pa[mt], vb, oacc[mt][nt]);
    }
  }

  // store attn output bf16, head-concat layout [win*49+tok][h*32+d]
  short* ao = aout + (size_t)win * NTOK * DMODEL;
#pragma unroll
  for (int mt = 0; mt < 4; ++mt)
#pragma unroll
    for (int r = 0; r < 4; ++r) {
      int row = mt * 16 + lhi * 4 + r;
      if (row < NTOK) {
#pragma unroll
        for (int nt = 0; nt < 2; ++nt)
          ao[row * DMODEL + h * DHEAD + nt * 16 + llo] = f2bf(oacc[mt][nt][r]);
      }
    }
}

// ---- final GEMM: out[200704,256] = aout @ w_out, fp32 store
__global__ __launch_bounds__(256, 2) void k_out(
    const short* __restrict__ aout, const short* __restrict__ woT,
    float* __restrict__ out) {
  __shared__ short At[64 * LDX];
  const int tid = threadIdx.x;
  const int wv = tid >> 6, lane = tid & 63;
  const int lhi = lane >> 4, llo = lane & 15;
  const size_t m0 = (size_t)blockIdx.x * 64;
#pragma unroll
  for (int i = 0; i < 8; ++i) {
    int c = tid + i * 256;          // 2048 chunks of 16B
    int row = c >> 5, cc = c & 31;
    *(int4*)&At[row * LDX + cc * 8] = *(const int4*)&aout[(m0 + row) * DMODEL + cc * 8];
  }
  __syncthreads();
  f32x4 acc[4][4] = {};
  for (int ks = 0; ks < 8; ++ks) {
    bf16x8 a[4], b[4];
#pragma unroll
    for (int mt = 0; mt < 4; ++mt)
      a[mt] = *(const bf16x8*)&At[(mt * 16 + llo) * LDX + ks * 32 + lhi * 8];
#pragma unroll
    for (int nt = 0; nt < 4; ++nt)
      b[nt] = *(const bf16x8*)&woT[(wv * 64 + nt * 16 + llo) * 256 + ks * 32 + lhi * 8];
#pragma unroll
    for (int nt = 0; nt < 4; ++nt)
#pragma unroll
      for (int mt = 0; mt < 4; ++mt) acc[mt][nt] = mfma16(a[mt], b[nt], acc[mt][nt]);
  }
#pragma unroll
  for (int mt = 0; mt < 4; ++mt)
#pragma unroll
    for (int nt = 0; nt < 4; ++nt)
#pragma unroll
      for (int r = 0; r < 4; ++r)
        out[(m0 + mt * 16 + lhi * 4 + r) * DMODEL + wv * 64 + nt * 16 + llo] = acc[mt][nt][r];
}

extern "C" void kernel_launch(void* const* d_in, const int* in_sizes, int n_in,
                              void* d_out, int out_size, void* d_ws, size_t ws_size,
                              hipStream_t stream) {
  const float* x     = (const float*)d_in[0];
  const float* gamma = (const float*)d_in[1];
  const float* wqkv  = (const float*)d_in[2];
  const float* memkv = (const float*)d_in[3];
  const float* btab  = (const float*)d_in[4];
  const float* wout  = (const float*)d_in[5];
  float* out = (float*)d_out;

  short* wqT  = (short*)d_ws;               // 768*256 bf16
  short* woT  = wqT + 768 * 256;            // 256*256 bf16
  short* aout = woT + 256 * 256;            // 200704*256 bf16 (~103 MB)

  k_convert<<<768, 256, 0, stream>>>(wqkv, wout, wqT, woT);
  k_attn<<<NWIN, 512, LDS_BYTES, stream>>>(x, gamma, wqT, memkv, btab, aout);
  k_out<<<200704 / 64, 256, 0, stream>>>(aout, woT, out);
}

// Round 2
// 742.918 us; speedup vs baseline: 1.1561x; 1.1561x over previous
//
#include <hip/hip_runtime.h>

typedef __attribute__((ext_vector_type(8))) short bf16x8;
typedef __attribute__((ext_vector_type(4))) float f32x4;

#define NWIN 4096
#define NTOK 49
#define NHEAD 8

__device__ __forceinline__ short f2bf(float f) {  // RNE float->bf16
  unsigned u = __float_as_uint(f);
  unsigned r = (u + 0x7fffu + ((u >> 16) & 1u)) >> 16;
  return (short)r;
}

__device__ __forceinline__ f32x4 mfma16(bf16x8 a, bf16x8 b, f32x4 c) {
  return __builtin_amdgcn_mfma_f32_16x16x32_bf16(a, b, c, 0, 0, 0);
}

// ---- prep: weight transposes, memB bf16, dense bias table [8][64][64] fp32
__global__ void k_prep(const float* __restrict__ wqkv, const float* __restrict__ wout,
                       const float* __restrict__ memkv, const float* __restrict__ btab,
                       short* __restrict__ wqT, short* __restrict__ woT,
                       short* __restrict__ memB, float* __restrict__ biasF) {
  int idx = blockIdx.x * 256 + threadIdx.x;
  if (idx < 768 * 256) { int n = idx >> 8, k = idx & 255; wqT[idx] = f2bf(wqkv[k * 768 + n]); }
  if (idx < 256 * 256) { int n = idx >> 8, k = idx & 255; woT[idx] = f2bf(wout[k * 256 + n]); }
  if (idx < 2048) memB[idx] = f2bf(memkv[idx]);
  if (idx < 32768) {   // bias[h][qt][col]: col>=53 -> -1e30 (pad keys), mem cols 0-3 -> 0
    int h = idx >> 12, qt = (idx >> 6) & 63, col = idx & 63;
    float b;
    if (col >= 53) b = -1e30f;
    else if (col < 4 || qt >= 49) b = 0.f;
    else {
      int t = col - 4;
      int r0 = qt / 7 - t / 7 + 6, r1 = qt % 7 - t % 7 + 6;
      b = btab[(r0 * 13 + r1) * NHEAD + h];
    }
    biasF[idx] = b;
  }
}

// ---- LN + QKV GEMM per window. 512 thr (8 waves = 8 heads). 2 blocks/CU target.
__global__ __launch_bounds__(512, 4) void k_lnqkv(
    const float* __restrict__ x, const float* __restrict__ gamma,
    const short* __restrict__ wqT, const float* __restrict__ memkv,
    short* __restrict__ qg, short* __restrict__ kg, short* __restrict__ vtg) {
  __shared__ short lds[18432];    // 36864 B: xn [64][264] (33792 B) overlaid later by vt 8*[32][72]
  const int tid = threadIdx.x;
  const int wv = tid >> 6, lane = tid & 63;
  const int lhi = lane >> 4, llo = lane & 15;
  const int win = blockIdx.x, h = wv;

  for (int j = tid; j < 8448; j += 512) ((int*)lds)[j] = 0;   // zero xn (pad rows)
  __syncthreads();

  // LayerNorm -> xn bf16 [64][264]
  const float* xwin = x + (size_t)win * (NTOK * 256);
  const float4 g4 = ((const float4*)gamma)[lane];
  for (int row = wv; row < NTOK; row += 8) {
    float4 v = ((const float4*)(xwin + row * 256))[lane];
    float s = v.x + v.y + v.z + v.w;
#pragma unroll
    for (int m = 1; m < 64; m <<= 1) s += __shfl_xor(s, m);
    float mu = s * (1.0f / 256.0f);
    float dx = v.x - mu, dy = v.y - mu, dz = v.z - mu, dw = v.w - mu;
    float s2 = dx * dx + dy * dy + dz * dz + dw * dw;
#pragma unroll
    for (int m = 1; m < 64; m <<= 1) s2 += __shfl_xor(s2, m);
    float rs = rsqrtf(s2 * (1.0f / 256.0f) + 1e-5f);
    short4 o;
    o.x = f2bf(dx * rs * g4.x); o.y = f2bf(dy * rs * g4.y);
    o.z = f2bf(dz * rs * g4.z); o.w = f2bf(dw * rs * g4.w);
    *(short4*)&lds[row * 264 + lane * 4] = o;
  }
  __syncthreads();

  const int nr = h * 32 + llo;
  // pass 1: q (2 tiles) + k (2 tiles)
  f32x4 a1[4][4] = {};
  for (int ks = 0; ks < 8; ++ks) {
    bf16x8 a[4];
#pragma unroll
    for (int mt = 0; mt < 4; ++mt)
      a[mt] = *(const bf16x8*)&lds[(mt * 16 + llo) * 264 + ks * 32 + lhi * 8];
    const int nrow[4] = {nr, nr + 16, nr + 256, nr + 272};
#pragma unroll
    for (int nt = 0; nt < 4; ++nt) {
      bf16x8 b = *(const bf16x8*)&wqT[nrow[nt] * 256 + ks * 32 + lhi * 8];
#pragma unroll
      for (int mt = 0; mt < 4; ++mt) a1[mt][nt] = mfma16(a[mt], b, a1[mt][nt]);
    }
  }
  // store q (scaled) and k, layout [pid=win*8+h][49][32] bf16
  {
    const float qscale = 0.17677669529663687f;
    short* qdst = qg + (size_t)(win * 8 + h) * (NTOK * 32);
    short* kdst = kg + (size_t)(win * 8 + h) * (NTOK * 32);
#pragma unroll
    for (int mt = 0; mt < 4; ++mt)
#pragma unroll
      for (int r = 0; r < 4; ++r) {
        int row = mt * 16 + lhi * 4 + r;
        if (row < NTOK) {
          qdst[row * 32 + llo]      = f2bf(a1[mt][0][r] * qscale);
          qdst[row * 32 + llo + 16] = f2bf(a1[mt][1][r] * qscale);
          kdst[row * 32 + llo]      = f2bf(a1[mt][2][r]);
          kdst[row * 32 + llo + 16] = f2bf(a1[mt][3][r]);
        }
      }
  }
  // pass 2: v (2 tiles)
  f32x4 a2[4][2] = {};
  for (int ks = 0; ks < 8; ++ks) {
    bf16x8 a[4];
#pragma unroll
    for (int mt = 0; mt < 4; ++mt)
      a[mt] = *(const bf16x8*)&lds[(mt * 16 + llo) * 264 + ks * 32 + lhi * 8];
    const int nrow[2] = {nr + 512, nr + 528};
#pragma unroll
    for (int nt = 0; nt < 2; ++nt) {
      bf16x8 b = *(const bf16x8*)&wqT[nrow[nt] * 256 + ks * 32 + lhi * 8];
#pragma unroll
      for (int mt = 0; mt < 4; ++mt) a2[mt][nt] = mfma16(a[mt], b, a2[mt][nt]);
    }
  }
  __syncthreads();          // xn dead
  for (int j = tid; j < 9216; j += 512) ((int*)lds)[j] = 0;   // zero vt region
  __syncthreads();

  // scatter v transposed into per-head [32 d][72] (keys: 0-3 mem, 4-52 tokens)
  short* vth = lds + wv * 2304;
#pragma unroll
  for (int mt = 0; mt < 4; ++mt)
#pragma unroll
    for (int r = 0; r < 4; ++r) {
      int row = mt * 16 + lhi * 4 + r;
      if (row < NTOK) {
        vth[llo * 72 + row + 4]        = f2bf(a2[mt][0][r]);
        vth[(llo + 16) * 72 + row + 4] = f2bf(a2[mt][1][r]);
      }
    }
#pragma unroll
  for (int i = 0; i < 2; ++i) {
    int e = lane + i * 64, m = e >> 5, d = e & 31;
    vth[d * 72 + m] = f2bf(memkv[1024 + (h * 4 + m) * 32 + d]);
  }
  // coalesced copy vt -> global [pid][32][64]
#pragma unroll
  for (int i = 0; i < 4; ++i) {
    int c = lane + i * 64, row = c >> 3, co = c & 7;
    bf16x8 t = *(const bf16x8*)&vth[row * 72 + co * 8];
    *(bf16x8*)&vtg[((size_t)(win * 8 + h) * 32 + row) * 64 + co * 8] = t;
  }
}

// ---- attention: 1 wave per (win,head), no barriers. 256 thr = 4 pairs.
__global__ __launch_bounds__(256, 4) void k_attn2(
    const short* __restrict__ qg, const short* __restrict__ kg,
    const short* __restrict__ vtg, const short* __restrict__ memB,
    const float* __restrict__ biasF, short* __restrict__ aout) {
  __shared__ short P[4][64 * 72];
  const int tid = threadIdx.x;
  const int wv = tid >> 6, lane = tid & 63;
  const int lhi = lane >> 4, llo = lane & 15;
  const int pid = blockIdx.x * 4 + wv;
  const int win = pid >> 3, h = pid & 7;

  const short* qp = qg + (size_t)pid * (NTOK * 32);
  const short* kp = kg + (size_t)pid * (NTOK * 32);
  const short* vp = vtg + (size_t)pid * (32 * 64);

  bf16x8 qa[4], kb[4];
#pragma unroll
  for (int mt = 0; mt < 4; ++mt)
    qa[mt] = *(const bf16x8*)&qp[(mt * 16 + llo) * 32 + lhi * 8];
  {  // nt=0 fragment: rows 0-3 come from memory-kv
    const short* p = (llo < 4) ? &memB[(h * 4 + llo) * 32] : &kp[(llo - 4) * 32];
    kb[0] = *(const bf16x8*)&p[lhi * 8];
  }
#pragma unroll
  for (int nt = 1; nt < 4; ++nt)
    kb[nt] = *(const bf16x8*)&kp[(nt * 16 + llo - 4) * 32 + lhi * 8];

  f32x4 sim[4][4] = {};
#pragma unroll
  for (int nt = 0; nt < 4; ++nt)
#pragma unroll
    for (int mt = 0; mt < 4; ++mt) sim[mt][nt] = mfma16(qa[mt], kb[nt], sim[mt][nt]);

  // softmax with precomputed bias (pad cols already -1e30 in table)
  short* Ph = P[wv];
  const float* bh = biasF + h * 4096;
#pragma unroll
  for (int mt = 0; mt < 4; ++mt)
#pragma unroll
    for (int r = 0; r < 4; ++r) {
      const int qt = mt * 16 + lhi * 4 + r;
      const float* br = bh + qt * 64;
      float vals[4];
#pragma unroll
      for (int nt = 0; nt < 4; ++nt) vals[nt] = sim[mt][nt][r] + br[nt * 16 + llo];
      float mx = fmaxf(fmaxf(vals[0], vals[1]), fmaxf(vals[2], vals[3]));
#pragma unroll
      for (int m = 1; m < 16; m <<= 1) mx = fmaxf(mx, __shfl_xor(mx, m));
      float p[4], sum = 0.f;
#pragma unroll
      for (int nt = 0; nt < 4; ++nt) { p[nt] = __expf(vals[nt] - mx); sum += p[nt]; }
#pragma unroll
      for (int m = 1; m < 16; m <<= 1) sum += __shfl_xor(sum, m);
      float inv = 1.0f / sum;
#pragma unroll
      for (int nt = 0; nt < 4; ++nt)
        Ph[qt * 72 + nt * 16 + llo] = f2bf(p[nt] * inv);
    }

  // PV: M=64, N=32, K=64
  f32x4 oacc[4][2] = {};
#pragma unroll
  for (int ks = 0; ks < 2; ++ks) {
    bf16x8 pa[4];
#pragma unroll
    for (int mt = 0; mt < 4; ++mt)
      pa[mt] = *(const bf16x8*)&Ph[(mt * 16 + llo) * 72 + ks * 32 + lhi * 8];
#pragma unroll
    for (int nt = 0; nt < 2; ++nt) {
      bf16x8 vb = *(const bf16x8*)&vp[(nt * 16 + llo) * 64 + ks * 32 + lhi * 8];
#pragma unroll
      for (int mt = 0; mt < 4; ++mt) oacc[mt][nt] = mfma16(pa[mt], vb, oacc[mt][nt]);
    }
  }

  short* ao = aout + (size_t)win * (NTOK * 256);
#pragma unroll
  for (int mt = 0; mt < 4; ++mt)
#pragma unroll
    for (int r = 0; r < 4; ++r) {
      int row = mt * 16 + lhi * 4 + r;
      if (row < NTOK) {
#pragma unroll
        for (int nt = 0; nt < 2; ++nt)
          ao[row * 256 + h * 32 + nt * 16 + llo] = f2bf(oacc[mt][nt][r]);
      }
    }
}

// ---- final GEMM: out[200704,256] = aout @ w_out, fp32
__global__ __launch_bounds__(256, 4) void k_out(
    const short* __restrict__ aout, const short* __restrict__ woT,
    float* __restrict__ out) {
  __shared__ short At[64 * 264];
  const int tid = threadIdx.x;
  const int wv = tid >> 6, lane = tid & 63;
  const int lhi = lane >> 4, llo = lane & 15;
  const size_t m0 = (size_t)blockIdx.x * 64;
#pragma unroll
  for (int i = 0; i < 8; ++i) {
    int c = tid + i * 256, row = c >> 5, cc = c & 31;
    *(int4*)&At[row * 264 + cc * 8] = *(const int4*)&aout[(m0 + row) * 256 + cc * 8];
  }
  __syncthreads();
  f32x4 acc[4][4] = {};
  for (int ks = 0; ks < 8; ++ks) {
    bf16x8 a[4], b[4];
#pragma unroll
    for (int mt = 0; mt < 4; ++mt)
      a[mt] = *(const bf16x8*)&At[(mt * 16 + llo) * 264 + ks * 32 + lhi * 8];
#pragma unroll
    for (int nt = 0; nt < 4; ++nt)
      b[nt] = *(const bf16x8*)&woT[(wv * 64 + nt * 16 + llo) * 256 + ks * 32 + lhi * 8];
#pragma unroll
    for (int nt = 0; nt < 4; ++nt)
#pragma unroll
      for (int mt = 0; mt < 4; ++mt) acc[mt][nt] = mfma16(a[mt], b[nt], acc[mt][nt]);
  }
#pragma unroll
  for (int mt = 0; mt < 4; ++mt)
#pragma unroll
    for (int nt = 0; nt < 4; ++nt)
#pragma unroll
      for (int r = 0; r < 4; ++r)
        out[(m0 + mt * 16 + lhi * 4 + r) * 256 + wv * 64 + nt * 16 + llo] = acc[mt][nt][r];
}

extern "C" void kernel_launch(void* const* d_in, const int* in_sizes, int n_in,
                              void* d_out, int out_size, void* d_ws, size_t ws_size,
                              hipStream_t stream) {
  const float* x     = (const float*)d_in[0];
  const float* gamma = (const float*)d_in[1];
  const float* wqkv  = (const float*)d_in[2];
  const float* memkv = (const float*)d_in[3];
  const float* btab  = (const float*)d_in[4];
  const float* wout  = (const float*)d_in[5];
  float* out = (float*)d_out;

  short* wqT   = (short*)d_ws;                 // 768*256
  short* woT   = wqT + 196608;                 // 256*256
  short* memB  = woT + 65536;                  // 2048
  float* biasF = (float*)(memB + 2048);        // 8*64*64 fp32
  short* qg    = (short*)(biasF + 32768);      // 32768*49*32 bf16 (+pad)
  short* kg    = qg + 51380224 + 1024;
  short* vtg   = kg + 51380224 + 1024;         // 32768*32*64 bf16
  short* aout  = vtg + 67108864;               // 200704*256 bf16

  k_prep<<<768, 256, 0, stream>>>(wqkv, wout, memkv, btab, wqT, woT, memB, biasF);
  k_lnqkv<<<NWIN, 512, 0, stream>>>(x, gamma, wqT, memkv, qg, kg, vtg);
  k_attn2<<<8192, 256, 0, stream>>>(qg, kg, vtg, memB, biasF, aout);
  k_out<<<3136, 256, 0, stream>>>(aout, woT, out);
}